// Round 10
// baseline (422.481 us; speedup 1.0000x reference)
//
#include <hip/hip_runtime.h>
#include <hip/hip_fp16.h>

namespace {

constexpr int W_RES = 320, H_RES = 240, BS = 4, VD = 128, NS = 256;
constexpr int NPIX = W_RES * H_RES;
constexpr float DENS_SCALE = 100.0f / 256.0f;
constexpr float TAU = 2e-3f;   // early-exit; adds <= ~4e-3 abs error
constexpr long long VOX = (long long)VD * VD * VD;  // 2,097,152

// Vector-of-2 half type exactly as the builtins define it (clang may spell it
// __fp16 or _Float16 depending on version; decltype sidesteps that).
using h2v = decltype(__builtin_amdgcn_cvt_pkrtz(0.0f, 0.0f));

__device__ __forceinline__ unsigned pkrtz(float lo, float hi) {
    h2v h = __builtin_amdgcn_cvt_pkrtz(lo, hi);
    return __builtin_bit_cast(unsigned, h);
}

__device__ __forceinline__ float fdot2u(unsigned a, unsigned b, float c) {
#if __has_builtin(__builtin_amdgcn_fdot2)
    return __builtin_amdgcn_fdot2(__builtin_bit_cast(h2v, a),
                                  __builtin_bit_cast(h2v, b), c, false);
#else
    __half2 ha, hb;
    __builtin_memcpy(&ha, &a, 4);
    __builtin_memcpy(&hb, &b, 4);
    return c + __half2float(__low2half(ha)) * __half2float(__low2half(hb)) +
           __half2float(__high2half(ha)) * __half2float(__high2half(hb));
#endif
}

__device__ __forceinline__ unsigned h2u(__half2 h) {
    unsigned u; __builtin_memcpy(&u, &h, 4); return u;
}

// (B,4,D,H,W) fp32 -> (B,D,H,W) 16B entries:
// entry[x] = {half2(R[x],R[x+1]), half2(G..), half2(B..), half2(D..)}, x=127 hi=0 pad.
__global__ void transpose_k(const float* __restrict__ vol, uint4* __restrict__ out) {
    long long tid = (long long)blockIdx.x * blockDim.x + threadIdx.x;
    if (tid >= (long long)BS * VOX) return;
    int b = (int)(tid >> 21);
    long long rem = tid & (VOX - 1);
    int x = (int)(rem & (VD - 1));
    const float* vb = vol + (long long)b * 4 * VOX + rem;
    bool pad = (x == VD - 1);
    float R0 = vb[0],        R1 = pad ? 0.0f : vb[1];
    float G0 = vb[VOX],      G1 = pad ? 0.0f : vb[VOX + 1];
    float B0 = vb[2 * VOX],  B1 = pad ? 0.0f : vb[2 * VOX + 1];
    float D0 = vb[3 * VOX],  D1 = pad ? 0.0f : vb[3 * VOX + 1];
    uint4 o;
    o.x = h2u(__floats2half2_rn(R0, R1));
    o.y = h2u(__floats2half2_rn(G0, G1));
    o.z = h2u(__floats2half2_rn(B0, B1));
    o.w = h2u(__floats2half2_rn(D0, D1));
    out[tid] = o;
}

struct St {
    uint4 p[4];       // corner-pair entries: (z0,y0) (z0,y1) (z1,y0) (z1,y1)
    unsigned wp[4];   // packed half2 (w*wlo, w*whi) per corner
};

struct Coord {
    int x0, y0, z0;
    float fx, fy, fz;
    bool fast;
};

__device__ __forceinline__ Coord mkc(float ix, float iy, float iz) {
    Coord c;
    float f;
    f = floorf(ix); c.fx = ix - f; c.x0 = (int)f;
    f = floorf(iy); c.fy = iy - f; c.y0 = (int)f;
    f = floorf(iz); c.fz = iz - f; c.z0 = (int)f;
    c.fast = ((unsigned)c.x0 < 128u) & ((unsigned)c.y0 < 127u) & ((unsigned)c.z0 < 127u);
    return c;
}

__device__ __forceinline__ void stage_fast(const uint4* __restrict__ vb,
                                           const Coord& c, St& st) {
    const uint4* r0 = vb + ((c.z0 * VD + c.y0) * VD + c.x0);
    const uint4* r1 = r0 + VD * VD;
    st.p[0] = r0[0];
    st.p[1] = r0[VD];
    st.p[2] = r1[0];
    st.p[3] = r1[VD];
    float wlo = 1.0f - c.fx, whi = c.fx;
    float wy0 = 1.0f - c.fy, wz0 = 1.0f - c.fz;
    float w00 = wz0 * wy0, w01 = wz0 * c.fy, w10 = c.fz * wy0, w11 = c.fz * c.fy;
    st.wp[0] = pkrtz(w00 * wlo, w00 * whi);
    st.wp[1] = pkrtz(w01 * wlo, w01 * whi);
    st.wp[2] = pkrtz(w10 * wlo, w10 * whi);
    st.wp[3] = pkrtz(w11 * wlo, w11 * whi);
}

__device__ __forceinline__ void stage_safe(const uint4* __restrict__ vb,
                                           const Coord& c, St& st) {
    int x0 = c.x0, y0 = c.y0, z0 = c.z0;
    bool in01x = ((unsigned)x0 < 128u);
    bool ism1 = (x0 == -1);
    // x0==-1: entry[0]=(v[0],v[1]); corner x=0 carries weight fx -> wlo=fx, whi=0.
    float wlo = in01x ? (1.0f - c.fx) : (ism1 ? c.fx : 0.0f);
    float whi = in01x ? c.fx : 0.0f;
    int bx = min(max(x0, 0), 127);

    float my0 = ((unsigned)y0 < 128u) ? 1.0f : 0.0f;
    float my1 = ((unsigned)(y0 + 1) < 128u) ? 1.0f : 0.0f;
    float mz0 = ((unsigned)z0 < 128u) ? 1.0f : 0.0f;
    float mz1 = ((unsigned)(z0 + 1) < 128u) ? 1.0f : 0.0f;
    int yc0 = min(max(y0, 0), 127), yc1 = min(max(y0 + 1, 0), 127);
    int zc0 = min(max(z0, 0), 127), zc1 = min(max(z0 + 1, 0), 127);

    st.p[0] = vb[(zc0 * VD + yc0) * VD + bx];
    st.p[1] = vb[(zc0 * VD + yc1) * VD + bx];
    st.p[2] = vb[(zc1 * VD + yc0) * VD + bx];
    st.p[3] = vb[(zc1 * VD + yc1) * VD + bx];

    float wy0 = (1.0f - c.fy) * my0, wy1 = c.fy * my1;
    float wz0 = (1.0f - c.fz) * mz0, wz1 = c.fz * mz1;
    float w00 = wz0 * wy0, w01 = wz0 * wy1, w10 = wz1 * wy0, w11 = wz1 * wy1;
    st.wp[0] = pkrtz(w00 * wlo, w00 * whi);
    st.wp[1] = pkrtz(w01 * wlo, w01 * whi);
    st.wp[2] = pkrtz(w10 * wlo, w10 * whi);
    st.wp[3] = pkrtz(w11 * wlo, w11 * whi);
}

__device__ __forceinline__ void consume(const St& st, float& T, float& wsum,
                                        float& aR, float& aG, float& aB) {
    float ar = 0, ag = 0, ab = 0, ad = 0;
#pragma unroll
    for (int i = 0; i < 4; ++i) {
        ar = fdot2u(st.p[i].x, st.wp[i], ar);
        ag = fdot2u(st.p[i].y, st.wp[i], ag);
        ab = fdot2u(st.p[i].z, st.wp[i], ab);
        ad = fdot2u(st.p[i].w, st.wp[i], ad);
    }
    float dsv = ad * DENS_SCALE;
    T *= (1.0f - dsv);
    float wgt = dsv * T;
    wsum += wgt;
    aR = fmaf(wgt, ar, aR);
    aG = fmaf(wgt, ag, aG);
    aB = fmaf(wgt, ab, aB);
}

// 1200 blocks, edge-first column order (silhouette/straggler tiles dispatch
// first; short center tiles backfill the drain as resident slots free up).
__global__ void __launch_bounds__(256, 3) raycast_k(const uint4* __restrict__ vol,
                                                    const float* __restrict__ tfm,
                                                    float* __restrict__ out) {
    int lane = threadIdx.x & 63;
    int wave = threadIdx.x >> 6;
    int bid = blockIdx.x;           // 0..1199
    int cr = bid / 60;              // column rank, edge-first
    int rem = bid % 60;
    int tx = (cr & 1) ? (19 - (cr >> 1)) : (cr >> 1);
    int ty = rem >> 2;              // 0..14
    int b = rem & 3;
    int x = tx * 16 + (lane & 15);
    int y = ty * 16 + wave * 4 + (lane >> 4);

    float X = -1.0f + 2.0f * x / (float)(W_RES - 1);
    float Y = -1.0f + 2.0f * y / (float)(H_RES - 1);
    const float dZ = 2.0f / (float)(NS - 1);

    const float* M = tfm + b * 16;
    float bxc = M[0] * X + M[1] * Y + M[3];
    float byc = M[4] * X + M[5] * Y + M[7];
    float bzc = M[8] * X + M[9] * Y + M[11];
    float bwc = M[12] * X + M[13] * Y + M[15];
    float m02 = M[2], m12 = M[6], m22 = M[10], m32 = M[14];

    const uint4* vb = vol + (long long)b * VOX;

    bool w1 = (fabsf(bwc - 1.0f) < 1e-6f) && (fabsf(m32) < 1e-6f);
    float lo = 0.0f, hi = (float)(NS - 1);
    if (w1) {
        const float LIM = 1.0078125f + 1e-5f;
        auto clipAxis = [&](float bb, float mm) {
            float A = bb - mm;  // g(s) = A + B*s
            float Bq = mm * dZ;
            if (fabsf(Bq) < 1e-9f) {
                if (fabsf(A) > LIM) { lo = 1.0f; hi = 0.0f; }
            } else {
                float s1 = (-LIM - A) / Bq, s2 = (LIM - A) / Bq;
                lo = fmaxf(lo, fminf(s1, s2));
                hi = fminf(hi, fmaxf(s1, s2));
            }
        };
        clipAxis(bxc, m02);
        clipAxis(byc, m12);
        clipAxis(bzc, m22);
    }
    int s_start = max(0, (int)ceilf(lo - 1e-3f));
    int s_end = min(NS - 1, (int)floorf(hi + 1e-3f));

    // wave-common bounds over valid lanes only
    int rs = (s_start <= s_end) ? s_start : 0x7fffffff;
    int re = (s_start <= s_end) ? s_end : -0x7fffffff;
#pragma unroll
    for (int off = 1; off < 64; off <<= 1) {
        rs = min(rs, __shfl_xor(rs, off));
        re = max(re, __shfl_xor(re, off));
    }

    // affine index coords (valid when w row trivial): i(s) = i0 + s*di
    float dix = m02 * dZ * 64.0f, ix0 = (bxc - m02) * 64.0f + 63.5f;
    float diy = m12 * dZ * 64.0f, iy0 = (byc - m12) * 64.0f + 63.5f;
    float diz = m22 * dZ * 64.0f, iz0 = (bzc - m22) * 64.0f + 63.5f;

    auto coords = [&](int s, float& ix, float& iy, float& iz) {
        float sf = (float)s;
        if (w1) {
            ix = fmaf(sf, dix, ix0);
            iy = fmaf(sf, diy, iy0);
            iz = fmaf(sf, diz, iz0);
        } else {
            float Z = fmaf(sf, dZ, -1.0f);
            float iw = 1.0f / fmaf(m32, Z, bwc);
            ix = fmaf(fmaf(m02, Z, bxc) * iw, 64.0f, 63.5f);
            iy = fmaf(fmaf(m12, Z, byc) * iw, 64.0f, 63.5f);
            iz = fmaf(fmaf(m22, Z, bzc) * iw, 64.0f, 63.5f);
        }
    };

    float T = 1.0f, wsum = 0.0f, aR = 0.0f, aG = 0.0f, aB = 0.0f;
    St S0, S1, S2, S3;

    for (int s = rs; s <= re; s += 4) {
        bool alive = (T >= TAU);
        bool g0 = (s >= s_start) & (s <= s_end) & alive;
        bool g1 = (s + 1 >= s_start) & (s + 1 <= s_end) & alive;
        bool g2 = (s + 2 >= s_start) & (s + 2 <= s_end) & alive;
        bool g3 = (s + 3 >= s_start) & (s + 3 <= s_end) & alive;
        Coord c0, c1, c2, c3;
        float ix, iy, iz;
        if (g0) { coords(s, ix, iy, iz); c0 = mkc(ix, iy, iz); }
        if (g1) { coords(s + 1, ix, iy, iz); c1 = mkc(ix, iy, iz); }
        if (g2) { coords(s + 2, ix, iy, iz); c2 = mkc(ix, iy, iz); }
        if (g3) { coords(s + 3, ix, iy, iz); c3 = mkc(ix, iy, iz); }
        bool fastAll = __all((g0 ? c0.fast : true) & (g1 ? c1.fast : true) &
                             (g2 ? c2.fast : true) & (g3 ? c3.fast : true));
        if (fastAll) {
            if (g0) stage_fast(vb, c0, S0);
            if (g1) stage_fast(vb, c1, S1);
            if (g2) stage_fast(vb, c2, S2);
            if (g3) stage_fast(vb, c3, S3);
        } else {
            if (g0) stage_safe(vb, c0, S0);
            if (g1) stage_safe(vb, c1, S1);
            if (g2) stage_safe(vb, c2, S2);
            if (g3) stage_safe(vb, c3, S3);
        }
        __builtin_amdgcn_sched_barrier(0);  // keep loads hoisted above consumes
        if (g0) consume(S0, T, wsum, aR, aG, aB);
        if (g1 & (T >= TAU)) consume(S1, T, wsum, aR, aG, aB);
        if (g2 & (T >= TAU)) consume(S2, T, wsum, aR, aG, aB);
        if (g3 & (T >= TAU)) consume(S3, T, wsum, aR, aG, aB);
        if (!__any((T >= TAU) & (s + 4 <= s_end))) break;
    }

    float scale = (1.0f - T) / (wsum + 1e-6f);
    int po = y * W_RES + x;
    float* ob = out + (long long)b * 3 * NPIX;
    ob[po] = aR * scale;
    ob[po + NPIX] = aG * scale;
    ob[po + 2 * NPIX] = aB * scale;
}

}  // namespace

extern "C" void kernel_launch(void* const* d_in, const int* in_sizes, int n_in,
                              void* d_out, int out_size, void* d_ws, size_t ws_size,
                              hipStream_t stream) {
    const float* vol = (const float*)d_in[0];  // (4,4,128,128,128) fp32
    const float* tfm = (const float*)d_in[1];  // (4,4,4) fp32
    float* out = (float*)d_out;                // (4,3,240,320) fp32

    uint4* v16 = (uint4*)d_ws;  // fp16 channel-paired x-dup volume, 134 MB
    (void)ws_size; (void)in_sizes; (void)n_in; (void)out_size;

    const long long nent = (long long)BS * VOX;  // 8,388,608 entries
    transpose_k<<<(int)((nent + 255) / 256), 256, 0, stream>>>(vol, v16);

    raycast_k<<<1200, 256, 0, stream>>>(v16, tfm, out);
}

// Round 11
// 208.011 us; speedup vs baseline: 2.0311x; 2.0311x over previous
//
#include <hip/hip_runtime.h>
#include <hip/hip_fp16.h>

namespace {

constexpr int W_RES = 320, H_RES = 240, BS = 4, VD = 128, NS = 256;
constexpr int NPIX = W_RES * H_RES;
constexpr int ACAP = 64;                                // steps covered by pass A
constexpr float DENS_SCALE = 100.0f / 256.0f / 255.0f;  // u8 units -> ds
constexpr float TAU = 5e-4f;
constexpr long long VOX = (long long)VD * VD * VD;      // 2,097,152

constexpr size_t VOL_BYTES = (size_t)BS * VOX * 8;      // 67,108,864
constexpr size_t CKPT_BYTES = (size_t)BS * NPIX * 16;   // 19,660,800

__device__ __forceinline__ unsigned h2u(__half2 h) {
    unsigned u; __builtin_memcpy(&u, &h, 4); return u;
}
__device__ __forceinline__ float pack_wT(float ws, float T) {
    return __builtin_bit_cast(float, h2u(__floats2half2_rn(ws, T)));
}
__device__ __forceinline__ void unpack_wT(float p, float& ws, float& T) {
    unsigned u = __builtin_bit_cast(unsigned, p);
    __half2 h; __builtin_memcpy(&h, &u, 4);
    ws = __half2float(__low2half(h)); T = __half2float(__high2half(h));
}

// Transpose (B,4,D,H,W) fp32 -> (B,D,H,W) of uint2 entries:
// entry[x] = (u8x4 voxel[x], u8x4 voxel[x+1]), voxel[128] == 0 pad.  [r6-proven]
__global__ void transpose_k(const float* __restrict__ vol, uint4* __restrict__ out) {
    long long tid = (long long)blockIdx.x * blockDim.x + threadIdx.x;
    const long long npair = (long long)BS * VOX / 2;
    if (tid >= npair) return;
    int b = (int)(tid / (VOX / 2));
    long long r = (tid - (long long)b * (VOX / 2)) * 2;
    int x = (int)(r & (VD - 1));
    bool last = (x == VD - 2);
    const float* vb = vol + (long long)b * 4 * VOX + r;
    float2 R = *(const float2*)(vb);
    float2 G = *(const float2*)(vb + VOX);
    float2 Bl = *(const float2*)(vb + 2 * VOX);
    float2 Dn = *(const float2*)(vb + 3 * VOX);
    float R2 = last ? 0.0f : vb[2];
    float G2 = last ? 0.0f : vb[VOX + 2];
    float B2 = last ? 0.0f : vb[2 * VOX + 2];
    float D2 = last ? 0.0f : vb[3 * VOX + 2];
    auto pk = [](float r_, float g_, float bl_, float d_) -> unsigned {
        unsigned ur = (unsigned)(r_ * 255.0f + 0.5f);
        unsigned ug = (unsigned)(g_ * 255.0f + 0.5f);
        unsigned ub = (unsigned)(bl_ * 255.0f + 0.5f);
        unsigned ud = (unsigned)(d_ * 255.0f + 0.5f);
        return ur | (ug << 8) | (ub << 16) | (ud << 24);
    };
    unsigned p0 = pk(R.x, G.x, Bl.x, Dn.x);
    unsigned p1 = pk(R.y, G.y, Bl.y, Dn.y);
    unsigned p2 = pk(R2, G2, B2, D2);
    uint4 o;
    o.x = p0; o.y = p1;
    o.z = p1; o.w = p2;
    out[tid] = o;
}

struct St {
    uint2 p[4];
    float wzy[4];
    float wlo, whi;
};

struct Coord {
    int x0, y0, z0;
    float fx, fy, fz;
    bool fast;
};

__device__ __forceinline__ Coord mkc(float ix, float iy, float iz) {
    Coord c;
    float f;
    f = floorf(ix); c.fx = ix - f; c.x0 = (int)f;
    f = floorf(iy); c.fy = iy - f; c.y0 = (int)f;
    f = floorf(iz); c.fz = iz - f; c.z0 = (int)f;
    c.fast = ((unsigned)c.x0 < 128u) & ((unsigned)c.y0 < 127u) & ((unsigned)c.z0 < 127u);
    return c;
}

__device__ __forceinline__ void stage_fast(const uint2* __restrict__ vb,
                                           const Coord& c, St& st) {
    const uint2* r0 = vb + ((c.z0 * VD + c.y0) * VD + c.x0);
    const uint2* r1 = r0 + VD * VD;
    st.p[0] = r0[0];
    st.p[1] = r0[VD];
    st.p[2] = r1[0];
    st.p[3] = r1[VD];
    st.wlo = 1.0f - c.fx;
    st.whi = c.fx;
    float wy0 = 1.0f - c.fy, wy1 = c.fy;
    float wz0 = 1.0f - c.fz, wz1 = c.fz;
    st.wzy[0] = wz0 * wy0; st.wzy[1] = wz0 * wy1;
    st.wzy[2] = wz1 * wy0; st.wzy[3] = wz1 * wy1;
}

__device__ __forceinline__ void stage_safe(const uint2* __restrict__ vb,
                                           const Coord& c, St& st) {
    int x0 = c.x0, y0 = c.y0, z0 = c.z0;
    bool in01x = ((unsigned)x0 < 128u);
    bool ism1 = (x0 == -1);
    st.wlo = in01x ? (1.0f - c.fx) : (ism1 ? c.fx : 0.0f);
    st.whi = in01x ? c.fx : 0.0f;
    int bx = min(max(x0, 0), 127);

    float my0 = ((unsigned)y0 < 128u) ? 1.0f : 0.0f;
    float my1 = ((unsigned)(y0 + 1) < 128u) ? 1.0f : 0.0f;
    float mz0 = ((unsigned)z0 < 128u) ? 1.0f : 0.0f;
    float mz1 = ((unsigned)(z0 + 1) < 128u) ? 1.0f : 0.0f;
    int yc0 = min(max(y0, 0), 127), yc1 = min(max(y0 + 1, 0), 127);
    int zc0 = min(max(z0, 0), 127), zc1 = min(max(z0 + 1, 0), 127);

    st.p[0] = vb[(zc0 * VD + yc0) * VD + bx];
    st.p[1] = vb[(zc0 * VD + yc1) * VD + bx];
    st.p[2] = vb[(zc1 * VD + yc0) * VD + bx];
    st.p[3] = vb[(zc1 * VD + yc1) * VD + bx];

    float wy0 = (1.0f - c.fy) * my0, wy1 = c.fy * my1;
    float wz0 = (1.0f - c.fz) * mz0, wz1 = c.fz * mz1;
    st.wzy[0] = wz0 * wy0; st.wzy[1] = wz0 * wy1;
    st.wzy[2] = wz1 * wy0; st.wzy[3] = wz1 * wy1;
}

__device__ __forceinline__ void consume(const St& st, float& T, float& wsum,
                                        float& aR, float& aG, float& aB) {
    float ar = 0, ag = 0, ab = 0, ad = 0;
#pragma unroll
    for (int i = 0; i < 4; ++i) {
        unsigned lo = st.p[i].x, hi = st.p[i].y;
        float wl = st.wzy[i] * st.wlo;
        float wh = st.wzy[i] * st.whi;
        ar = fmaf(wl, (float)(lo & 255u), ar);
        ag = fmaf(wl, (float)((lo >> 8) & 255u), ag);
        ab = fmaf(wl, (float)((lo >> 16) & 255u), ab);
        ad = fmaf(wl, (float)(lo >> 24), ad);
        ar = fmaf(wh, (float)(hi & 255u), ar);
        ag = fmaf(wh, (float)((hi >> 8) & 255u), ag);
        ab = fmaf(wh, (float)((hi >> 16) & 255u), ab);
        ad = fmaf(wh, (float)(hi >> 24), ad);
    }
    float dsv = ad * DENS_SCALE;
    T *= (1.0f - dsv);
    float wgt = dsv * T;
    wsum += wgt;
    aR = fmaf(wgt, ar, aR);
    aG = fmaf(wgt, ag, aG);
    aB = fmaf(wgt, ab, aB);
}

struct Ray {
    float bxc, byc, bzc, bwc, m02, m12, m22, m32;
    bool w1;
    int s_start, s_end;
};

// Identical source in passes A and B -> identical per-lane s_start/s_end,
// so the per-lane A/B domain partition is exact.
__device__ __forceinline__ Ray make_ray(const float* __restrict__ M, int x, int y) {
    Ray r;
    float X = -1.0f + 2.0f * x / (float)(W_RES - 1);
    float Y = -1.0f + 2.0f * y / (float)(H_RES - 1);
    const float dZ = 2.0f / (float)(NS - 1);
    r.bxc = M[0] * X + M[1] * Y + M[3];
    r.byc = M[4] * X + M[5] * Y + M[7];
    r.bzc = M[8] * X + M[9] * Y + M[11];
    r.bwc = M[12] * X + M[13] * Y + M[15];
    r.m02 = M[2]; r.m12 = M[6]; r.m22 = M[10]; r.m32 = M[14];
    r.w1 = (fabsf(r.bwc - 1.0f) < 1e-6f) && (fabsf(r.m32) < 1e-6f);
    float lo = 0.0f, hi = (float)(NS - 1);
    if (r.w1) {
        const float LIM = 1.0078125f + 1e-5f;
        auto clipAxis = [&](float bb, float mm) {
            float A = bb - mm;  // g(s) = A + B*s
            float Bq = mm * dZ;
            if (fabsf(Bq) < 1e-9f) {
                if (fabsf(A) > LIM) { lo = 1.0f; hi = 0.0f; }
            } else {
                float s1 = (-LIM - A) / Bq, s2 = (LIM - A) / Bq;
                lo = fmaxf(lo, fminf(s1, s2));
                hi = fminf(hi, fmaxf(s1, s2));
            }
        };
        clipAxis(r.bxc, r.m02);
        clipAxis(r.byc, r.m12);
        clipAxis(r.bzc, r.m22);
    }
    r.s_start = max(0, (int)ceilf(lo - 1e-3f));
    r.s_end = min(NS - 1, (int)floorf(hi + 1e-3f));
    return r;
}

__device__ __forceinline__ void ray_coords(const Ray& r, int s,
                                           float& ix, float& iy, float& iz) {
    const float dZ = 2.0f / (float)(NS - 1);
    float Z = fmaf((float)s, dZ, -1.0f);
    float gx = fmaf(r.m02, Z, r.bxc);
    float gy = fmaf(r.m12, Z, r.byc);
    float gz = fmaf(r.m22, Z, r.bzc);
    if (!r.w1) {
        float iw = 1.0f / fmaf(r.m32, Z, r.bwc);
        gx *= iw; gy *= iw; gz *= iw;
    }
    ix = fmaf(gx, 64.0f, 63.5f);
    iy = fmaf(gy, 64.0f, 63.5f);
    iz = fmaf(gz, 64.0f, 63.5f);
}

// March the per-lane domain [sLo, sHi] (empty -> lane inactive). r6 body.
__device__ __forceinline__ void march(const uint2* __restrict__ vb, const Ray& r,
                                      int sLo, int sHi, float& T, float& wsum,
                                      float& aR, float& aG, float& aB) {
    bool ok = (sLo <= sHi);
    int lo_l = ok ? sLo : 0x7fffffff;
    int hi_l = ok ? sHi : (-0x7fffffff - 1);
#pragma unroll
    for (int off = 1; off < 64; off <<= 1) {
        lo_l = min(lo_l, __shfl_xor(lo_l, off));
        hi_l = max(hi_l, __shfl_xor(hi_l, off));
    }
    if (lo_l > hi_l) return;

    St S0, S1, S2;
    for (int s = lo_l; s <= hi_l; s += 3) {
        bool alive = ok & (T >= TAU);
        bool g0 = (s >= sLo) & (s <= sHi) & alive;
        bool g1 = (s + 1 >= sLo) & (s + 1 <= sHi) & alive;
        bool g2 = (s + 2 >= sLo) & (s + 2 <= sHi) & alive;
        Coord c0, c1, c2;
        float ix, iy, iz;
        if (g0) { ray_coords(r, s, ix, iy, iz); c0 = mkc(ix, iy, iz); }
        if (g1) { ray_coords(r, s + 1, ix, iy, iz); c1 = mkc(ix, iy, iz); }
        if (g2) { ray_coords(r, s + 2, ix, iy, iz); c2 = mkc(ix, iy, iz); }
        bool fastAll = __all((g0 ? c0.fast : true) & (g1 ? c1.fast : true) &
                             (g2 ? c2.fast : true));
        if (fastAll) {
            if (g0) stage_fast(vb, c0, S0);
            if (g1) stage_fast(vb, c1, S1);
            if (g2) stage_fast(vb, c2, S2);
        } else {
            if (g0) stage_safe(vb, c0, S0);
            if (g1) stage_safe(vb, c1, S1);
            if (g2) stage_safe(vb, c2, S2);
        }
        __builtin_amdgcn_sched_barrier(0);  // keep loads hoisted above consumes
        if (g0) consume(S0, T, wsum, aR, aG, aB);
        if (g1 & (T >= TAU)) consume(S1, T, wsum, aR, aG, aB);
        if (g2 & (T >= TAU)) consume(S2, T, wsum, aR, aG, aB);
        if (!__any(ok & (T >= TAU) & (s + 3 <= sHi))) break;
    }
}

// Pass A: first ACAP steps of every ray (uniform duration, no tail).
__global__ void __launch_bounds__(256) raycastA_k(const uint2* __restrict__ vol,
                                                  const float* __restrict__ tfm,
                                                  float4* __restrict__ ckpt) {
    int lane = threadIdx.x & 63;
    int wave = threadIdx.x >> 6;
    int b = blockIdx.z;
    int x = blockIdx.x * 16 + (lane & 15);
    int y = blockIdx.y * 16 + wave * 4 + (lane >> 4);

    Ray r = make_ray(tfm + b * 16, x, y);
    const uint2* vb = vol + (long long)b * VOX;

    float T = 1.0f, wsum = 0.0f, aR = 0.0f, aG = 0.0f, aB = 0.0f;
    int sLo = r.s_start;
    int sHi = min(r.s_end, r.s_start + ACAP - 1);
    if (r.s_start > r.s_end) { sLo = 1; sHi = 0; }
    march(vb, r, sLo, sHi, T, wsum, aR, aG, aB);

    ckpt[(long long)b * NPIX + y * W_RES + x] =
        make_float4(aR, aG, aB, pack_wT(wsum, T));
}

// Pass B: 2 segments over the surviving remainder. Lanes whose checkpoint
// T < TAU are inactive (kills r8's re-march waste).
__global__ void __launch_bounds__(256) raycastB_k(const uint2* __restrict__ vol,
                                                  const float* __restrict__ tfm,
                                                  const float4* __restrict__ ckpt,
                                                  float4* __restrict__ seg) {
    int lane = threadIdx.x & 63;
    int wave = threadIdx.x >> 6;
    int k = blockIdx.z & 1;
    int b = blockIdx.z >> 1;
    int x = blockIdx.x * 16 + (lane & 15);
    int y = blockIdx.y * 16 + wave * 4 + (lane >> 4);

    Ray r = make_ray(tfm + b * 16, x, y);
    const uint2* vb = vol + (long long)b * VOX;
    long long pidx = (long long)b * NPIX + y * W_RES + x;

    float T = 1.0f, wsum = 0.0f, aR = 0.0f, aG = 0.0f, aB = 0.0f;

    int sLo = 1, sHi = 0;  // empty by default
    if (r.s_start <= r.s_end) {
        int base = r.s_start + ACAP;
        if (base <= r.s_end) {
            float wsA, TA;
            unpack_wT(ckpt[pidx].w, wsA, TA);
            if (TA >= TAU) {
                int remLen = r.s_end - base + 1;
                int L = (remLen + 1) >> 1;  // ceil(remLen/2)
                sLo = base + k * L;
                sHi = min(r.s_end, sLo + L - 1);
                if (sLo > r.s_end) { sLo = 1; sHi = 0; }
            }
        }
    }
    march(vb, r, sLo, sHi, T, wsum, aR, aG, aB);

    seg[(long long)k * BS * NPIX + pidx] = make_float4(aR, aG, aB, pack_wT(wsum, T));
}

// Pass C: exact associative composite of {A, B0, B1}.
__global__ void combine_k(const float4* __restrict__ ckpt,
                          const float4* __restrict__ seg,
                          float* __restrict__ out) {
    int tid = blockIdx.x * blockDim.x + threadIdx.x;
    if (tid >= BS * NPIX) return;
    float4 a0 = ckpt[tid];
    float ws, Tg;
    unpack_wT(a0.w, ws, Tg);
    float aR = a0.x, aG = a0.y, aB = a0.z;
#pragma unroll
    for (int k = 0; k < 2; ++k) {
        float4 a = seg[(long long)k * BS * NPIX + tid];
        float wsk, Tk;
        unpack_wT(a.w, wsk, Tk);
        aR = fmaf(Tg, a.x, aR);
        aG = fmaf(Tg, a.y, aG);
        aB = fmaf(Tg, a.z, aB);
        ws = fmaf(Tg, wsk, ws);
        Tg *= Tk;
    }
    float scale = (1.0f - Tg) / (ws + 1e-6f) * (1.0f / 255.0f);
    int b = tid / NPIX;
    int pix = tid - b * NPIX;
    float* ob = out + (long long)b * 3 * NPIX;
    ob[pix] = aR * scale;
    ob[pix + NPIX] = aG * scale;
    ob[pix + 2 * NPIX] = aB * scale;
}

}  // namespace

extern "C" void kernel_launch(void* const* d_in, const int* in_sizes, int n_in,
                              void* d_out, int out_size, void* d_ws, size_t ws_size,
                              hipStream_t stream) {
    const float* vol = (const float*)d_in[0];  // (4,4,128,128,128) fp32
    const float* tfm = (const float*)d_in[1];  // (4,4,4) fp32
    float* out = (float*)d_out;                // (4,3,240,320) fp32

    unsigned char* ws = (unsigned char*)d_ws;
    uint4* v8 = (uint4*)ws;                                   // 67.1 MB volume
    float4* ckpt = (float4*)(ws + VOL_BYTES);                 // 19.7 MB
    float4* seg = (float4*)(ws + VOL_BYTES + CKPT_BYTES);     // 39.3 MB (2 segs)
    (void)ws_size; (void)in_sizes; (void)n_in; (void)out_size;

    const long long npair = (long long)BS * VOX / 2;  // 4,194,304
    transpose_k<<<(int)((npair + 255) / 256), 256, 0, stream>>>(vol, v8);

    dim3 gA(W_RES / 16, H_RES / 16, BS);       // 20x15x4
    raycastA_k<<<gA, 256, 0, stream>>>((const uint2*)v8, tfm, ckpt);

    dim3 gB(W_RES / 16, H_RES / 16, BS * 2);   // 20x15x8
    raycastB_k<<<gB, 256, 0, stream>>>((const uint2*)v8, tfm, ckpt, seg);

    combine_k<<<(BS * NPIX + 255) / 256, 256, 0, stream>>>(ckpt, seg, out);
}

// Round 13
// 202.228 us; speedup vs baseline: 2.0891x; 1.0286x over previous
//
#include <hip/hip_runtime.h>
#include <hip/hip_fp16.h>

namespace {

constexpr int W_RES = 320, H_RES = 240, BS = 4, VD = 128, NS = 256;
constexpr int NPIX = W_RES * H_RES;
constexpr int ACAP = 48;   // pass-A step cap
constexpr int KSEG = 2;    // survivor segments
constexpr float DENS_SCALE = 100.0f / 256.0f / 255.0f;  // u8 units -> ds
constexpr float TAU = 5e-4f;
constexpr long long VOX = (long long)VD * VD * VD;

constexpr size_t VOL_B = (size_t)BS * VOX * 8;        // 67,108,864
constexpr size_t CKPT_B = (size_t)BS * NPIX * 16;     // 19,660,800
constexpr size_t SEG_B = (size_t)KSEG * BS * NPIX * 16;  // 39,321,600
constexpr size_t WL_B = (size_t)BS * NPIX * 4;        // 4,915,200

__device__ __forceinline__ int wmin(int v) {
#pragma unroll
    for (int o = 1; o < 64; o <<= 1) v = min(v, __shfl_xor(v, o));
    return v;
}
__device__ __forceinline__ int wmax(int v) {
#pragma unroll
    for (int o = 1; o < 64; o <<= 1) v = max(v, __shfl_xor(v, o));
    return v;
}

__device__ __forceinline__ unsigned h2u(__half2 h) {
    unsigned u; __builtin_memcpy(&u, &h, 4); return u;
}
// pack (wsum, T) as half2; survivor flag in sign bit of T-half.
__device__ __forceinline__ float pack_wT(float ws, float T, bool surv) {
    __half2 h = __floats2half2_rn(ws, surv ? -T : T);
    return __builtin_bit_cast(float, h2u(h));
}
__device__ __forceinline__ void unpack_wT(float p, float& ws, float& T, bool& surv) {
    unsigned u = __builtin_bit_cast(unsigned, p);
    surv = (u >> 31) != 0u;
    __half2 h; __builtin_memcpy(&h, &u, 4);
    ws = __half2float(__low2half(h));
    T = fabsf(__half2float(__high2half(h)));
}

// Transpose (B,4,D,H,W) fp32 -> (B,D,H,W) uint2: (u8x4 v[x], u8x4 v[x+1]).
__global__ void transpose_k(const float* __restrict__ vol, uint4* __restrict__ out,
                            unsigned* __restrict__ ctr) {
    long long tid = (long long)blockIdx.x * blockDim.x + threadIdx.x;
    if (tid == 0) *ctr = 0u;
    const long long npair = (long long)BS * VOX / 2;
    if (tid >= npair) return;
    int b = (int)(tid / (VOX / 2));
    long long r = (tid - (long long)b * (VOX / 2)) * 2;
    int x = (int)(r & (VD - 1));
    bool last = (x == VD - 2);
    const float* vb = vol + (long long)b * 4 * VOX + r;
    float2 R = *(const float2*)(vb);
    float2 G = *(const float2*)(vb + VOX);
    float2 Bl = *(const float2*)(vb + 2 * VOX);
    float2 Dn = *(const float2*)(vb + 3 * VOX);
    float R2 = last ? 0.0f : vb[2];
    float G2 = last ? 0.0f : vb[VOX + 2];
    float B2 = last ? 0.0f : vb[2 * VOX + 2];
    float D2 = last ? 0.0f : vb[3 * VOX + 2];
    auto pk = [](float r_, float g_, float bl_, float d_) -> unsigned {
        unsigned ur = (unsigned)(r_ * 255.0f + 0.5f);
        unsigned ug = (unsigned)(g_ * 255.0f + 0.5f);
        unsigned ub = (unsigned)(bl_ * 255.0f + 0.5f);
        unsigned ud = (unsigned)(d_ * 255.0f + 0.5f);
        return ur | (ug << 8) | (ub << 16) | (ud << 24);
    };
    unsigned p0 = pk(R.x, G.x, Bl.x, Dn.x);
    unsigned p1 = pk(R.y, G.y, Bl.y, Dn.y);
    unsigned p2 = pk(R2, G2, B2, D2);
    uint4 o;
    o.x = p0; o.y = p1;
    o.z = p1; o.w = p2;
    out[tid] = o;
}

struct St {
    uint2 p[4];
    float wzy[4];
    float wlo, whi;
};

struct Coord {
    int x0, y0, z0;
    float fx, fy, fz;
    bool fast;
};

__device__ __forceinline__ Coord mkc(float ix, float iy, float iz) {
    Coord c;
    float f;
    f = floorf(ix); c.fx = ix - f; c.x0 = (int)f;
    f = floorf(iy); c.fy = iy - f; c.y0 = (int)f;
    f = floorf(iz); c.fz = iz - f; c.z0 = (int)f;
    c.fast = ((unsigned)c.x0 < 128u) & ((unsigned)c.y0 < 127u) & ((unsigned)c.z0 < 127u);
    return c;
}

__device__ __forceinline__ void stage_fast(const uint2* __restrict__ vb,
                                           const Coord& c, St& st) {
    unsigned idx = (unsigned)((c.z0 * VD + c.y0) * VD + c.x0);
    st.p[0] = vb[idx];
    st.p[1] = vb[idx + VD];
    st.p[2] = vb[idx + VD * VD];
    st.p[3] = vb[idx + VD * VD + VD];
    st.wlo = 1.0f - c.fx;
    st.whi = c.fx;
    float wy0 = 1.0f - c.fy, wy1 = c.fy;
    float wz0 = 1.0f - c.fz, wz1 = c.fz;
    st.wzy[0] = wz0 * wy0; st.wzy[1] = wz0 * wy1;
    st.wzy[2] = wz1 * wy0; st.wzy[3] = wz1 * wy1;
}

// Guard-free variant (all corners known in-box).
__device__ __forceinline__ void stage_fast_u(const uint2* __restrict__ vb,
                                             float ix, float iy, float iz, St& st) {
    float fx0 = floorf(ix), fy0 = floorf(iy), fz0 = floorf(iz);
    float fx = ix - fx0, fy = iy - fy0, fz = iz - fz0;
    unsigned x0 = (unsigned)(int)fx0, y0 = (unsigned)(int)fy0, z0 = (unsigned)(int)fz0;
    unsigned idx = (((z0 << 7) + y0) << 7) + x0;
    st.p[0] = vb[idx];
    st.p[1] = vb[idx + VD];
    st.p[2] = vb[idx + VD * VD];
    st.p[3] = vb[idx + VD * VD + VD];
    st.wlo = 1.0f - fx;
    st.whi = fx;
    float wy0 = 1.0f - fy, wz0 = 1.0f - fz;
    st.wzy[0] = wz0 * wy0; st.wzy[1] = wz0 * fy;
    st.wzy[2] = fz * wy0;  st.wzy[3] = fz * fy;
}

__device__ __forceinline__ void stage_safe(const uint2* __restrict__ vb,
                                           const Coord& c, St& st) {
    int x0 = c.x0, y0 = c.y0, z0 = c.z0;
    bool in01x = ((unsigned)x0 < 128u);
    bool ism1 = (x0 == -1);
    st.wlo = in01x ? (1.0f - c.fx) : (ism1 ? c.fx : 0.0f);
    st.whi = in01x ? c.fx : 0.0f;
    int bx = min(max(x0, 0), 127);

    float my0 = ((unsigned)y0 < 128u) ? 1.0f : 0.0f;
    float my1 = ((unsigned)(y0 + 1) < 128u) ? 1.0f : 0.0f;
    float mz0 = ((unsigned)z0 < 128u) ? 1.0f : 0.0f;
    float mz1 = ((unsigned)(z0 + 1) < 128u) ? 1.0f : 0.0f;
    int yc0 = min(max(y0, 0), 127), yc1 = min(max(y0 + 1, 0), 127);
    int zc0 = min(max(z0, 0), 127), zc1 = min(max(z0 + 1, 0), 127);

    st.p[0] = vb[(unsigned)((zc0 * VD + yc0) * VD + bx)];
    st.p[1] = vb[(unsigned)((zc0 * VD + yc1) * VD + bx)];
    st.p[2] = vb[(unsigned)((zc1 * VD + yc0) * VD + bx)];
    st.p[3] = vb[(unsigned)((zc1 * VD + yc1) * VD + bx)];

    float wy0 = (1.0f - c.fy) * my0, wy1 = c.fy * my1;
    float wz0 = (1.0f - c.fz) * mz0, wz1 = c.fz * mz1;
    st.wzy[0] = wz0 * wy0; st.wzy[1] = wz0 * wy1;
    st.wzy[2] = wz1 * wy0; st.wzy[3] = wz1 * wy1;
}

__device__ __forceinline__ void consume(const St& st, float& T, float& wsum,
                                        float& aR, float& aG, float& aB) {
    float ar = 0, ag = 0, ab = 0, ad = 0;
#pragma unroll
    for (int i = 0; i < 4; ++i) {
        unsigned lo = st.p[i].x, hi = st.p[i].y;
        float wl = st.wzy[i] * st.wlo;
        float wh = st.wzy[i] * st.whi;
        ar = fmaf(wl, (float)(lo & 255u), ar);
        ag = fmaf(wl, (float)((lo >> 8) & 255u), ag);
        ab = fmaf(wl, (float)((lo >> 16) & 255u), ab);
        ad = fmaf(wl, (float)(lo >> 24), ad);
        ar = fmaf(wh, (float)(hi & 255u), ar);
        ag = fmaf(wh, (float)((hi >> 8) & 255u), ag);
        ab = fmaf(wh, (float)((hi >> 16) & 255u), ab);
        ad = fmaf(wh, (float)(hi >> 24), ad);
    }
    float dsv = ad * DENS_SCALE;
    T *= (1.0f - dsv);
    float wgt = dsv * T;
    wsum += wgt;
    aR = fmaf(wgt, ar, aR);
    aG = fmaf(wgt, ag, aG);
    aB = fmaf(wgt, ab, aB);
}

struct Ray {
    float bxc, byc, bzc, bwc, m02, m12, m22, m32;
    bool w1;
    int s_start, s_end;   // some-corner-valid range
    int f_lo, f_hi;       // all-corners-in-box (guard-free) range
};

__device__ __forceinline__ Ray make_ray(const float* __restrict__ M, int x, int y) {
    Ray r;
    float X = -1.0f + 2.0f * x / (float)(W_RES - 1);
    float Y = -1.0f + 2.0f * y / (float)(H_RES - 1);
    const float dZ = 2.0f / (float)(NS - 1);
    r.bxc = M[0] * X + M[1] * Y + M[3];
    r.byc = M[4] * X + M[5] * Y + M[7];
    r.bzc = M[8] * X + M[9] * Y + M[11];
    r.bwc = M[12] * X + M[13] * Y + M[15];
    r.m02 = M[2]; r.m12 = M[6]; r.m22 = M[10]; r.m32 = M[14];
    r.w1 = (fabsf(r.bwc - 1.0f) < 1e-6f) && (fabsf(r.m32) < 1e-6f);
    float lo = 0.0f, hi = (float)(NS - 1);
    float flo = 0.0f, fhi = (float)(NS - 1);
    if (r.w1) {
        auto clip2 = [](float A, float Bq, float gl, float gh, float& l, float& h) {
            if (fabsf(Bq) < 1e-9f) {
                if (A < gl || A > gh) { l = 1.0f; h = 0.0f; }
            } else {
                float s1 = (gl - A) / Bq, s2 = (gh - A) / Bq;
                l = fmaxf(l, fminf(s1, s2));
                h = fminf(h, fmaxf(s1, s2));
            }
        };
        // g(s) = (b - m) + m*dZ*s
        const float LIM = 1.0078125f + 1e-5f;
        clip2(r.bxc - r.m02, r.m02 * dZ, -LIM, LIM, lo, hi);
        clip2(r.byc - r.m12, r.m12 * dZ, -LIM, LIM, lo, hi);
        clip2(r.bzc - r.m22, r.m22 * dZ, -LIM, LIM, lo, hi);
        // fast: ix in [0,128), iy/iz in [0,127)
        clip2(r.bxc - r.m02, r.m02 * dZ, -0.9921875f, 1.0078125f, flo, fhi);
        clip2(r.byc - r.m12, r.m12 * dZ, -0.9921875f, 0.9921875f, flo, fhi);
        clip2(r.bzc - r.m22, r.m22 * dZ, -0.9921875f, 0.9921875f, flo, fhi);
    } else {
        flo = 1.0f; fhi = 0.0f;
    }
    r.s_start = max(0, (int)ceilf(lo - 1e-3f));
    r.s_end = min(NS - 1, (int)floorf(hi + 1e-3f));
    r.f_lo = max(0, (int)ceilf(flo + 0.05f));   // shrink inward: boundary -> guarded
    r.f_hi = min(NS - 1, (int)floorf(fhi - 0.05f));
    return r;
}

__device__ __forceinline__ void ray_coords(const Ray& r, int s,
                                           float& ix, float& iy, float& iz) {
    const float dZ = 2.0f / (float)(NS - 1);
    float Z = fmaf((float)s, dZ, -1.0f);
    float gx = fmaf(r.m02, Z, r.bxc);
    float gy = fmaf(r.m12, Z, r.byc);
    float gz = fmaf(r.m22, Z, r.bzc);
    if (!r.w1) {
        float iw = 1.0f / fmaf(r.m32, Z, r.bwc);
        gx *= iw; gy *= iw; gz *= iw;
    }
    ix = fmaf(gx, 64.0f, 63.5f);
    iy = fmaf(gy, 64.0f, 63.5f);
    iz = fmaf(gz, 64.0f, 63.5f);
}

// Guarded march over wave-uniform [wLo,wHi], per-lane domain [sLo,sHi].
// NOTE: chunk spillover means samples up to wHi+2 may be touched; callers must
// ensure sHi (the guard) never extends past a region someone else processes.
__device__ __forceinline__ void march_g(const uint2* __restrict__ vb, const Ray& r,
                                        int sLo, int sHi, int wLo, int wHi,
                                        float& T, float& wsum, float& aR, float& aG,
                                        float& aB) {
    St S0, S1, S2;
    for (int s = wLo; s <= wHi; s += 3) {
        bool alive = (T >= TAU);
        bool g0 = (s >= sLo) & (s <= sHi) & alive;
        bool g1 = (s + 1 >= sLo) & (s + 1 <= sHi) & alive;
        bool g2 = (s + 2 >= sLo) & (s + 2 <= sHi) & alive;
        Coord c0, c1, c2;
        float ix, iy, iz;
        if (g0) { ray_coords(r, s, ix, iy, iz); c0 = mkc(ix, iy, iz); }
        if (g1) { ray_coords(r, s + 1, ix, iy, iz); c1 = mkc(ix, iy, iz); }
        if (g2) { ray_coords(r, s + 2, ix, iy, iz); c2 = mkc(ix, iy, iz); }
        bool fastAll = __all((g0 ? c0.fast : true) & (g1 ? c1.fast : true) &
                             (g2 ? c2.fast : true));
        if (fastAll) {
            if (g0) stage_fast(vb, c0, S0);
            if (g1) stage_fast(vb, c1, S1);
            if (g2) stage_fast(vb, c2, S2);
        } else {
            if (g0) stage_safe(vb, c0, S0);
            if (g1) stage_safe(vb, c1, S1);
            if (g2) stage_safe(vb, c2, S2);
        }
        __builtin_amdgcn_sched_barrier(0);
        if (g0) consume(S0, T, wsum, aR, aG, aB);
        if (g1 & (T >= TAU)) consume(S1, T, wsum, aR, aG, aB);
        if (g2 & (T >= TAU)) consume(S2, T, wsum, aR, aG, aB);
        if (!__any((T >= TAU) & (s + 3 <= sHi))) break;
    }
}

// Pass A: [s_start, s_start+ACAP) with guard-free interior window; writes ckpt
// and appends surviving pixel ids to the worklist.
__global__ void __launch_bounds__(256) raycastA_k(const uint2* __restrict__ vol,
                                                  const float* __restrict__ tfm,
                                                  float4* __restrict__ ckpt,
                                                  unsigned* __restrict__ wl,
                                                  unsigned* __restrict__ ctr) {
    int lane = threadIdx.x & 63;
    int wave = threadIdx.x >> 6;
    int bid = blockIdx.x;            // 0..1199, edge-first in x
    int cr = bid / 60, rem = bid % 60;
    int tx = (cr & 1) ? 19 - (cr >> 1) : (cr >> 1);
    int ty = rem >> 2;
    int b = rem & 3;
    int x = tx * 16 + (lane & 15);
    int y = ty * 16 + wave * 4 + (lane >> 4);

    Ray r = make_ray(tfm + b * 16, x, y);
    const uint2* vb = vol + (long long)b * VOX;
    bool valid = (r.s_start <= r.s_end);
    int capHi = min(r.s_end, r.s_start + ACAP - 1);

    float T = 1.0f, ws = 0.0f, aR = 0.0f, aG = 0.0f, aB = 0.0f;
    int rsW = wmin(valid ? r.s_start : 0x7fffffff);
    int reW = wmax(valid ? capHi : (-0x7fffffff - 1));

    if (rsW <= reW) {
        bool allV = __all(valid);
        int fLo = max(r.f_lo, r.s_start);
        int fHi = min(r.f_hi, capHi);
        int fl = (fLo <= fHi) ? fLo : NS;   // empty-fast sentinel
        int fh = (fLo <= fHi) ? fHi : -1;
        int fLoW = wmax(fl), fHiW = wmin(fh);
        if (allV && fLoW <= fHiW) {
            // R12 BUG FIX: clamp guard to fLoW-1 — chunk spillover past the wave
            // window was double-counting samples the fast loop also processes.
            march_g(vb, r, r.s_start, min(capHi, fLoW - 1), rsW, fLoW - 1,
                    T, ws, aR, aG, aB);
            int nIt = (fHiW - fLoW + 1) / 3;
            int s = fLoW;
            int fastEnd = fLoW + nIt * 3;
            while (s < fastEnd) {
                St S0, S1, S2;
                float ix, iy, iz;
                ray_coords(r, s, ix, iy, iz);     stage_fast_u(vb, ix, iy, iz, S0);
                ray_coords(r, s + 1, ix, iy, iz); stage_fast_u(vb, ix, iy, iz, S1);
                ray_coords(r, s + 2, ix, iy, iz); stage_fast_u(vb, ix, iy, iz, S2);
                __builtin_amdgcn_sched_barrier(0);
                consume(S0, T, ws, aR, aG, aB);
                consume(S1, T, ws, aR, aG, aB);
                consume(S2, T, ws, aR, aG, aB);
                s += 3;
                if (!__any(T >= TAU)) break;
            }
            march_g(vb, r, s, capHi, s, reW, T, ws, aR, aG, aB);
        } else {
            march_g(vb, r, r.s_start, capHi, rsW, reW, T, ws, aR, aG, aB);
        }
    }

    bool surv = valid && (T >= TAU) && (r.s_start + ACAP <= r.s_end);
    unsigned long long m = __ballot(surv);
    if (m) {
        int cnt = __popcll(m);
        unsigned base = 0;
        if (lane == 0) base = atomicAdd(ctr, (unsigned)cnt);
        base = (unsigned)__shfl((int)base, 0);
        if (surv) {
            unsigned pos = (unsigned)__popcll(m & ((1ull << lane) - 1ull));
            wl[base + pos] = (unsigned)(b * NPIX + y * W_RES + x);
        }
    }
    ckpt[(long long)b * NPIX + y * W_RES + x] =
        make_float4(aR, aG, aB, pack_wT(ws, T, surv));
}

// Pass B: dense grid-stride over survivors x KSEG segments.
__global__ void __launch_bounds__(256) raycastB_k(const uint2* __restrict__ vol,
                                                  const float* __restrict__ tfm,
                                                  const unsigned* __restrict__ wl,
                                                  const unsigned* __restrict__ ctr,
                                                  float4* __restrict__ seg) {
    int nS = (int)*ctr;
    long long total = (long long)nS * KSEG;
    int tid0 = blockIdx.x * blockDim.x + threadIdx.x;
    int stride = gridDim.x * blockDim.x;
    for (long long t = tid0; __any(t < total); t += stride) {
        bool act = (t < total);
        int si = act ? (int)(t % nS) : 0;
        int k = act ? (int)(t / nS) : 0;
        unsigned pid = act ? wl[si] : 0u;
        int b = (int)(pid / NPIX);
        int p = (int)(pid % NPIX);
        int y = p / W_RES, x = p - y * W_RES;
        Ray r = make_ray(tfm + b * 16, x, y);
        const uint2* vb = vol + (long long)b * VOX;
        int base = r.s_start + ACAP;
        int remn = r.s_end - base + 1;
        int L = (remn + KSEG - 1) / KSEG;
        int sLo = base + k * L;
        int sHi = min(r.s_end, sLo + L - 1);
        if (!act || remn <= 0) { sLo = 1; sHi = 0; }
        bool ok = (sLo <= sHi);
        int wLo = wmin(ok ? sLo : 0x7fffffff);
        int wHi = wmax(ok ? sHi : (-0x7fffffff - 1));
        float T = 1.0f, ws = 0.0f, aR = 0.0f, aG = 0.0f, aB = 0.0f;
        if (wLo <= wHi) march_g(vb, r, sLo, sHi, wLo, wHi, T, ws, aR, aG, aB);
        if (act)
            seg[(long long)k * BS * NPIX + pid] =
                make_float4(aR, aG, aB, pack_wT(ws, T, false));
    }
}

// Pass C: composite ckpt (+ segs for survivors), normalize, write out.
__global__ void combine_k(const float4* __restrict__ ckpt,
                          const float4* __restrict__ seg,
                          float* __restrict__ out) {
    int tid = blockIdx.x * blockDim.x + threadIdx.x;
    if (tid >= BS * NPIX) return;
    float4 a0 = ckpt[tid];
    float ws, Tg; bool surv;
    unpack_wT(a0.w, ws, Tg, surv);
    float aR = a0.x, aG = a0.y, aB = a0.z;
    if (surv) {
#pragma unroll
        for (int k = 0; k < KSEG; ++k) {
            float4 a = seg[(long long)k * BS * NPIX + tid];
            float wsk, Tk; bool d;
            unpack_wT(a.w, wsk, Tk, d);
            aR = fmaf(Tg, a.x, aR);
            aG = fmaf(Tg, a.y, aG);
            aB = fmaf(Tg, a.z, aB);
            ws = fmaf(Tg, wsk, ws);
            Tg *= Tk;
        }
    }
    float scale = (1.0f - Tg) / (ws + 1e-6f) * (1.0f / 255.0f);
    int b = tid / NPIX;
    int pix = tid - b * NPIX;
    float* ob = out + (long long)b * 3 * NPIX;
    ob[pix] = aR * scale;
    ob[pix + NPIX] = aG * scale;
    ob[pix + 2 * NPIX] = aB * scale;
}

}  // namespace

extern "C" void kernel_launch(void* const* d_in, const int* in_sizes, int n_in,
                              void* d_out, int out_size, void* d_ws, size_t ws_size,
                              hipStream_t stream) {
    const float* vol = (const float*)d_in[0];  // (4,4,128,128,128) fp32
    const float* tfm = (const float*)d_in[1];  // (4,4,4) fp32
    float* out = (float*)d_out;                // (4,3,240,320) fp32

    unsigned char* ws = (unsigned char*)d_ws;
    uint4* v8 = (uint4*)ws;                                       // 67.1 MB
    float4* ckpt = (float4*)(ws + VOL_B);                         // 19.7 MB
    float4* seg = (float4*)(ws + VOL_B + CKPT_B);                 // 39.3 MB
    unsigned* wl = (unsigned*)(ws + VOL_B + CKPT_B + SEG_B);      // 4.9 MB
    unsigned* ctr = (unsigned*)(ws + VOL_B + CKPT_B + SEG_B + WL_B);
    (void)ws_size; (void)in_sizes; (void)n_in; (void)out_size;

    const long long npair = (long long)BS * VOX / 2;
    transpose_k<<<(int)((npair + 255) / 256), 256, 0, stream>>>(vol, v8, ctr);

    raycastA_k<<<1200, 256, 0, stream>>>((const uint2*)v8, tfm, ckpt, wl, ctr);
    raycastB_k<<<512, 256, 0, stream>>>((const uint2*)v8, tfm, wl, ctr, seg);
    combine_k<<<(BS * NPIX + 255) / 256, 256, 0, stream>>>(ckpt, seg, out);
}

// Round 14
// 155.387 us; speedup vs baseline: 2.7189x; 1.3014x over previous
//
#include <hip/hip_runtime.h>
#include <hip/hip_fp16.h>

namespace {

constexpr int W_RES = 320, H_RES = 240, BS = 4, VD = 128, NS = 256;
constexpr int NPIX = W_RES * H_RES;
constexpr int ACAP = 48;   // pass-A step cap
constexpr int KSEG = 2;    // survivor segments
constexpr int E = 133;     // extended dim: true coords [-2..130], 2-voxel zero border
constexpr long long EVOX = (long long)E * E * E;  // 2,352,637
constexpr float DENS_SCALE = 100.0f / 256.0f / 255.0f;  // u8 units -> ds
constexpr float TAU = 5e-4f;
constexpr long long VOX = (long long)VD * VD * VD;

constexpr size_t VOL_B = ((size_t)BS * EVOX * 8 + 255) & ~(size_t)255;  // ~75.3 MB
constexpr size_t CKPT_B = (size_t)BS * NPIX * 16;       // 19,660,800
constexpr size_t SEG_B = (size_t)KSEG * BS * NPIX * 16; // 39,321,600
constexpr size_t WL_B = (size_t)BS * NPIX * 4;          // 4,915,200

__device__ __forceinline__ int wmin(int v) {
#pragma unroll
    for (int o = 1; o < 64; o <<= 1) v = min(v, __shfl_xor(v, o));
    return v;
}
__device__ __forceinline__ int wmax(int v) {
#pragma unroll
    for (int o = 1; o < 64; o <<= 1) v = max(v, __shfl_xor(v, o));
    return v;
}

__device__ __forceinline__ unsigned h2u(__half2 h) {
    unsigned u; __builtin_memcpy(&u, &h, 4); return u;
}
// pack (wsum, T) as half2; survivor flag in sign bit of T-half.
__device__ __forceinline__ float pack_wT(float ws, float T, bool surv) {
    __half2 h = __floats2half2_rn(ws, surv ? -T : T);
    return __builtin_bit_cast(float, h2u(h));
}
__device__ __forceinline__ void unpack_wT(float p, float& ws, float& T, bool& surv) {
    unsigned u = __builtin_bit_cast(unsigned, p);
    surv = (u >> 31) != 0u;
    __half2 h; __builtin_memcpy(&h, &u, 4);
    ws = __half2float(__low2half(h));
    T = fabsf(__half2float(__high2half(h)));
}

// Build the EXTENDED x-pair u8 volume: for each (b, ze, ye, xe) with true
// coords (x0,y0,z0) = (xe-2, ye-2, ze-2):
//   entry = ( u8x4 vox(x0,y0,z0), u8x4 vox(x0+1,y0,z0) ),  vox()=0 outside.
// Zero border makes grid_sample's zeros-padding implicit: border voxels
// contribute 0 no matter the interpolation weight.
__global__ void transpose_k(const float* __restrict__ vol, uint2* __restrict__ out,
                            unsigned* __restrict__ ctr) {
    long long tid = (long long)blockIdx.x * blockDim.x + threadIdx.x;
    if (tid == 0) *ctr = 0u;
    if (tid >= (long long)BS * EVOX) return;
    int b = (int)(tid / EVOX);
    long long rem = tid - (long long)b * EVOX;
    int ze = (int)(rem / (E * E));
    int r2 = (int)(rem - (long long)ze * (E * E));
    int ye = r2 / E;
    int xe = r2 - ye * E;
    int x0 = xe - 2, y0 = ye - 2, z0 = ze - 2;

    unsigned lo = 0u, hi = 0u;
    bool yz_in = ((unsigned)y0 < 128u) & ((unsigned)z0 < 128u);
    if (yz_in) {
        const float* vb = vol + (long long)b * 4 * VOX + ((long long)z0 * VD + y0) * VD;
        auto pk = [&](int x) -> unsigned {
            float r_ = vb[x], g_ = vb[x + VOX], bl_ = vb[x + 2 * VOX],
                  d_ = vb[x + 3 * VOX];
            unsigned ur = (unsigned)(r_ * 255.0f + 0.5f);
            unsigned ug = (unsigned)(g_ * 255.0f + 0.5f);
            unsigned ub = (unsigned)(bl_ * 255.0f + 0.5f);
            unsigned ud = (unsigned)(d_ * 255.0f + 0.5f);
            return ur | (ug << 8) | (ub << 16) | (ud << 24);
        };
        if ((unsigned)x0 < 128u) lo = pk(x0);
        if ((unsigned)(x0 + 1) < 128u) hi = pk(x0 + 1);
    }
    out[tid] = make_uint2(lo, hi);
}

struct St {
    uint2 p[4];
    float wzy[4];
    float wlo, whi;
};

struct Ray {
    float bxc, byc, bzc, bwc, m02, m12, m22, m32;
    bool w1;
    int s_start, s_end;
};

__device__ __forceinline__ Ray make_ray(const float* __restrict__ M, int x, int y) {
    Ray r;
    float X = -1.0f + 2.0f * x / (float)(W_RES - 1);
    float Y = -1.0f + 2.0f * y / (float)(H_RES - 1);
    const float dZ = 2.0f / (float)(NS - 1);
    r.bxc = M[0] * X + M[1] * Y + M[3];
    r.byc = M[4] * X + M[5] * Y + M[7];
    r.bzc = M[8] * X + M[9] * Y + M[11];
    r.bwc = M[12] * X + M[13] * Y + M[15];
    r.m02 = M[2]; r.m12 = M[6]; r.m22 = M[10]; r.m32 = M[14];
    r.w1 = (fabsf(r.bwc - 1.0f) < 1e-6f) && (fabsf(r.m32) < 1e-6f);
    float lo = 0.0f, hi = (float)(NS - 1);
    if (r.w1) {
        const float LIM = 1.0078125f + 1e-5f;  // some corner valid <=> |g| < 64.5/64
        auto clipAxis = [&](float A, float Bq) {
            if (fabsf(Bq) < 1e-9f) {
                if (fabsf(A) > LIM) { lo = 1.0f; hi = 0.0f; }
            } else {
                float s1 = (-LIM - A) / Bq, s2 = (LIM - A) / Bq;
                lo = fmaxf(lo, fminf(s1, s2));
                hi = fminf(hi, fmaxf(s1, s2));
            }
        };
        clipAxis(r.bxc - r.m02, r.m02 * dZ);
        clipAxis(r.byc - r.m12, r.m12 * dZ);
        clipAxis(r.bzc - r.m22, r.m22 * dZ);
    }
    r.s_start = max(0, (int)ceilf(lo - 1e-3f));
    r.s_end = min(NS - 1, (int)floorf(hi + 1e-3f));
    return r;
}

__device__ __forceinline__ void ray_coords(const Ray& r, int s,
                                           float& ix, float& iy, float& iz) {
    const float dZ = 2.0f / (float)(NS - 1);
    float Z = fmaf((float)s, dZ, -1.0f);
    float gx = fmaf(r.m02, Z, r.bxc);
    float gy = fmaf(r.m12, Z, r.byc);
    float gz = fmaf(r.m22, Z, r.bzc);
    if (!r.w1) {
        float iw = 1.0f / fmaf(r.m32, Z, r.bwc);
        gx *= iw; gy *= iw; gz *= iw;
    }
    ix = fmaf(gx, 64.0f, 63.5f);
    iy = fmaf(gy, 64.0f, 63.5f);
    iz = fmaf(gz, 64.0f, 63.5f);
}

// Uniform sample: clamp to extended box (identity for in-range coords), no
// validity masks or clamped corner indices needed — border voxels are zero.
// The per-lane range mask [sLo,sHi] is folded into the x-weights (A/B split
// boundaries are not geometric, so this mask is still required).
__device__ __forceinline__ void sample_u(const uint2* __restrict__ vb, const Ray& r,
                                         int s, int sLo, int sHi, St& st) {
    float ix, iy, iz;
    ray_coords(r, s, ix, iy, iz);
    ix = fminf(fmaxf(ix, -1.5f), 129.5f);
    iy = fminf(fmaxf(iy, -1.5f), 129.5f);
    iz = fminf(fmaxf(iz, -1.5f), 129.5f);
    float fxf = floorf(ix), fyf = floorf(iy), fzf = floorf(iz);
    float fx = ix - fxf, fy = iy - fyf, fz = iz - fzf;
    int x2 = (int)fxf + 2, y2 = (int)fyf + 2, z2 = (int)fzf + 2;  // [0..131]
    unsigned idx = (unsigned)((z2 * E + y2) * E + x2);
    st.p[0] = vb[idx];
    st.p[1] = vb[idx + E];
    st.p[2] = vb[idx + E * E];
    st.p[3] = vb[idx + E * E + E];
    float m = ((s >= sLo) & (s <= sHi)) ? 1.0f : 0.0f;
    st.wlo = (1.0f - fx) * m;
    st.whi = fx * m;
    float wy0 = 1.0f - fy, wz0 = 1.0f - fz;
    st.wzy[0] = wz0 * wy0; st.wzy[1] = wz0 * fy;
    st.wzy[2] = fz * wy0;  st.wzy[3] = fz * fy;
}

__device__ __forceinline__ void consume(const St& st, float& T, float& wsum,
                                        float& aR, float& aG, float& aB) {
    float ar = 0, ag = 0, ab = 0, ad = 0;
#pragma unroll
    for (int i = 0; i < 4; ++i) {
        unsigned lo = st.p[i].x, hi = st.p[i].y;
        float wl = st.wzy[i] * st.wlo;
        float wh = st.wzy[i] * st.whi;
        ar = fmaf(wl, (float)(lo & 255u), ar);
        ag = fmaf(wl, (float)((lo >> 8) & 255u), ag);
        ab = fmaf(wl, (float)((lo >> 16) & 255u), ab);
        ad = fmaf(wl, (float)(lo >> 24), ad);
        ar = fmaf(wh, (float)(hi & 255u), ar);
        ag = fmaf(wh, (float)((hi >> 8) & 255u), ag);
        ab = fmaf(wh, (float)((hi >> 16) & 255u), ab);
        ad = fmaf(wh, (float)(hi >> 24), ad);
    }
    float dsv = ad * DENS_SCALE;
    T *= (1.0f - dsv);
    float wgt = dsv * T;
    wsum += wgt;
    aR = fmaf(wgt, ar, aR);
    aG = fmaf(wgt, ag, aG);
    aB = fmaf(wgt, ab, aB);
}

// March per-lane [sLo,sHi] over the wave-union window; single uniform path.
__device__ __forceinline__ void march_u(const uint2* __restrict__ vb, const Ray& r,
                                        int sLo, int sHi, float& T, float& ws,
                                        float& aR, float& aG, float& aB) {
    bool ok = (sLo <= sHi);
    int wLo = wmin(ok ? sLo : 0x7fffffff);
    int wHi = wmax(ok ? sHi : (-0x7fffffff - 1));
    if (wLo > wHi) return;
    for (int s = wLo; s <= wHi; s += 4) {
        if (T >= TAU) {  // dead/inactive lanes stop issuing loads
            St S0, S1, S2, S3;
            sample_u(vb, r, s, sLo, sHi, S0);
            sample_u(vb, r, s + 1, sLo, sHi, S1);
            sample_u(vb, r, s + 2, sLo, sHi, S2);
            sample_u(vb, r, s + 3, sLo, sHi, S3);
            __builtin_amdgcn_sched_barrier(0);  // keep 16 loads batched
            consume(S0, T, ws, aR, aG, aB);
            consume(S1, T, ws, aR, aG, aB);
            consume(S2, T, ws, aR, aG, aB);
            consume(S3, T, ws, aR, aG, aB);
        }
        if (!__any((T >= TAU) & (s + 4 <= sHi))) break;
    }
}

// Pass A: first ACAP steps; writes ckpt, appends survivors to worklist.
__global__ void __launch_bounds__(256) raycastA_k(const uint2* __restrict__ vol,
                                                  const float* __restrict__ tfm,
                                                  float4* __restrict__ ckpt,
                                                  unsigned* __restrict__ wl,
                                                  unsigned* __restrict__ ctr) {
    int lane = threadIdx.x & 63;
    int wave = threadIdx.x >> 6;
    int bid = blockIdx.x;            // edge-first column order
    int cr = bid / 60, rem = bid % 60;
    int tx = (cr & 1) ? 19 - (cr >> 1) : (cr >> 1);
    int ty = rem >> 2;
    int b = rem & 3;
    int x = tx * 16 + (lane & 15);
    int y = ty * 16 + wave * 4 + (lane >> 4);

    Ray r = make_ray(tfm + b * 16, x, y);
    const uint2* vb = vol + (long long)b * EVOX;
    bool valid = (r.s_start <= r.s_end);
    int sLo = valid ? r.s_start : 1;
    int sHi = valid ? min(r.s_end, r.s_start + ACAP - 1) : 0;

    float T = 1.0f, ws = 0.0f, aR = 0.0f, aG = 0.0f, aB = 0.0f;
    march_u(vb, r, sLo, sHi, T, ws, aR, aG, aB);

    bool surv = valid && (T >= TAU) && (r.s_start + ACAP <= r.s_end);
    unsigned long long m = __ballot(surv);
    if (m) {
        int cnt = __popcll(m);
        unsigned base = 0;
        if (lane == 0) base = atomicAdd(ctr, (unsigned)cnt);
        base = (unsigned)__shfl((int)base, 0);
        if (surv) {
            unsigned pos = (unsigned)__popcll(m & ((1ull << lane) - 1ull));
            wl[base + pos] = (unsigned)(b * NPIX + y * W_RES + x);
        }
    }
    ckpt[(long long)b * NPIX + y * W_RES + x] =
        make_float4(aR, aG, aB, pack_wT(ws, T, surv));
}

// Pass B: dense grid-stride over survivors x KSEG segments.
__global__ void __launch_bounds__(256) raycastB_k(const uint2* __restrict__ vol,
                                                  const float* __restrict__ tfm,
                                                  const unsigned* __restrict__ wl,
                                                  const unsigned* __restrict__ ctr,
                                                  float4* __restrict__ seg) {
    int nS = (int)*ctr;
    long long total = (long long)nS * KSEG;
    int tid0 = blockIdx.x * blockDim.x + threadIdx.x;
    int stride = gridDim.x * blockDim.x;
    for (long long t = tid0; __any(t < total); t += stride) {
        bool act = (t < total);
        int si = act ? (int)(t % nS) : 0;
        int k = act ? (int)(t / nS) : 0;
        unsigned pid = act ? wl[si] : 0u;
        int b = (int)(pid / NPIX);
        int p = (int)(pid % NPIX);
        int y = p / W_RES, x = p - y * W_RES;
        Ray r = make_ray(tfm + b * 16, x, y);
        const uint2* vb = vol + (long long)b * EVOX;
        int base = r.s_start + ACAP;
        int remn = r.s_end - base + 1;
        int L = (remn + KSEG - 1) / KSEG;
        int sLo = base + k * L;
        int sHi = min(r.s_end, sLo + L - 1);
        if (!act || remn <= 0) { sLo = 1; sHi = 0; }
        float T = 1.0f, ws = 0.0f, aR = 0.0f, aG = 0.0f, aB = 0.0f;
        march_u(vb, r, sLo, sHi, T, ws, aR, aG, aB);
        if (act)
            seg[(long long)k * BS * NPIX + pid] =
                make_float4(aR, aG, aB, pack_wT(ws, T, false));
    }
}

// Pass C: composite ckpt (+ segs for survivors), normalize, write out.
__global__ void combine_k(const float4* __restrict__ ckpt,
                          const float4* __restrict__ seg,
                          float* __restrict__ out) {
    int tid = blockIdx.x * blockDim.x + threadIdx.x;
    if (tid >= BS * NPIX) return;
    float4 a0 = ckpt[tid];
    float ws, Tg; bool surv;
    unpack_wT(a0.w, ws, Tg, surv);
    float aR = a0.x, aG = a0.y, aB = a0.z;
    if (surv) {
#pragma unroll
        for (int k = 0; k < KSEG; ++k) {
            float4 a = seg[(long long)k * BS * NPIX + tid];
            float wsk, Tk; bool d;
            unpack_wT(a.w, wsk, Tk, d);
            aR = fmaf(Tg, a.x, aR);
            aG = fmaf(Tg, a.y, aG);
            aB = fmaf(Tg, a.z, aB);
            ws = fmaf(Tg, wsk, ws);
            Tg *= Tk;
        }
    }
    float scale = (1.0f - Tg) / (ws + 1e-6f) * (1.0f / 255.0f);
    int b = tid / NPIX;
    int pix = tid - b * NPIX;
    float* ob = out + (long long)b * 3 * NPIX;
    ob[pix] = aR * scale;
    ob[pix + NPIX] = aG * scale;
    ob[pix + 2 * NPIX] = aB * scale;
}

}  // namespace

extern "C" void kernel_launch(void* const* d_in, const int* in_sizes, int n_in,
                              void* d_out, int out_size, void* d_ws, size_t ws_size,
                              hipStream_t stream) {
    const float* vol = (const float*)d_in[0];  // (4,4,128,128,128) fp32
    const float* tfm = (const float*)d_in[1];  // (4,4,4) fp32
    float* out = (float*)d_out;                // (4,3,240,320) fp32

    unsigned char* ws = (unsigned char*)d_ws;
    uint2* v8 = (uint2*)ws;                                       // 75.3 MB ext vol
    float4* ckpt = (float4*)(ws + VOL_B);                         // 19.7 MB
    float4* seg = (float4*)(ws + VOL_B + CKPT_B);                 // 39.3 MB
    unsigned* wl = (unsigned*)(ws + VOL_B + CKPT_B + SEG_B);      // 4.9 MB
    unsigned* ctr = (unsigned*)(ws + VOL_B + CKPT_B + SEG_B + WL_B);
    (void)ws_size; (void)in_sizes; (void)n_in; (void)out_size;

    const long long nent = (long long)BS * EVOX;  // 9,410,548
    transpose_k<<<(int)((nent + 255) / 256), 256, 0, stream>>>(vol, v8, ctr);

    raycastA_k<<<1200, 256, 0, stream>>>((const uint2*)v8, tfm, ckpt, wl, ctr);
    raycastB_k<<<512, 256, 0, stream>>>((const uint2*)v8, tfm, wl, ctr, seg);
    combine_k<<<(BS * NPIX + 255) / 256, 256, 0, stream>>>(ckpt, seg, out);
}